// Round 5
// baseline (107.706 us; speedup 1.0000x reference)
//
#include <hip/hip_runtime.h>

#define NN 10000
#define NE 40000

typedef __attribute__((ext_vector_type(8))) short bf16x8;
typedef __attribute__((ext_vector_type(4))) float f32x4;
typedef __attribute__((ext_vector_type(8))) unsigned short u16x8;

__device__ inline unsigned short bf16rne(float f) {
  union { float f; unsigned u; } v; v.f = f;
  return (unsigned short)((v.u + 0x7FFFu + ((v.u >> 16) & 1u)) >> 16);
}

__device__ inline void gl_lds16(const unsigned short* g, unsigned short* l) {
  __builtin_amdgcn_global_load_lds(
      (const __attribute__((address_space(1))) void*)g,
      (__attribute__((address_space(3))) void*)l, 16, 0, 0);
}

// ew2 [128 x 2048] f32 -> bf16 MFMA-B fragment order.
// elem j of lane l, col-tile ct, k-chunk kk = B[kk*32+(l>>4)*8+j][ct*16+(l&15)]
// at ushort index ct*2048 + kk*512 + l*8 + j.
__global__ void k_reorder(const float* __restrict__ ew2, unsigned short* __restrict__ out) {
  const int l  = threadIdx.x & 63;
  const int kk = threadIdx.x >> 6;
  const int ct = blockIdx.x;
  const int col = ct * 16 + (l & 15);
  const int g = l >> 4;
  u16x8 v;
#pragma unroll
  for (int j = 0; j < 8; ++j) v[j] = bf16rne(ew2[(kk * 32 + g * 8 + j) * 2048 + col]);
  *reinterpret_cast<u16x8*>(out + ((size_t)(ct * 2048 + kk * 512 + l * 8))) = v;
}

// ew1 [16 x 128] f32 -> bf16 B-frag, K padded to 32 with zeros. 8 col-tiles.
__global__ void k_reorder_e(const float* __restrict__ ew1, unsigned short* __restrict__ out) {
  const int l  = threadIdx.x & 63;
  const int ct = threadIdx.x >> 6;  // 512 threads -> 8 tiles
  const int g = l >> 4;
  u16x8 v;
#pragma unroll
  for (int j = 0; j < 8; ++j) {
    int k = g * 8 + j;
    v[j] = (k < 16) ? bf16rne(ew1[k * 128 + ct * 16 + (l & 15)]) : (unsigned short)0;
  }
  *reinterpret_cast<u16x8*>(out + ((size_t)(ct * 64 + l) * 8)) = v;
}

// out[n,KO] = (relu?)(xin[n,KI]) @ root[KI,KO] + bias[KO]
template <int KI, int KO, bool RELU_IN>
__global__ void k_root(const float* __restrict__ xin, const float* __restrict__ root,
                       const float* __restrict__ bias, float* __restrict__ out) {
  int idx = blockIdx.x * 256 + threadIdx.x;
  if (idx >= NN * KO) return;
  int n = idx / KO, o = idx % KO;
  float acc = bias[o];
#pragma unroll
  for (int k = 0; k < KI; ++k) {
    float v = xin[n * KI + k];
    if (RELU_IN) v = fmaxf(v, 0.f);
    acc += v * root[k * KO + o];
  }
  out[idx] = acc;
}

// Fused per-edge kernel: 64 edges/block, 4 waves.
// H = relu(eattr@ew1+eb1) via MFMA; W = relu(H@ew2+eb2) fused with x[src]
// contraction. B-tiles streamed per-wave via global_load_lds into a private
// triple-buffer (depth-3 counted-vmcnt pipeline, NO barriers in the loop).
// Coalesced atomics: 16 consecutive lanes = 16 consecutive cols of one edge.
template <int CI, int CO, bool RELU_IN>
__global__ __launch_bounds__(256, 2) void k_edge(
    const int* __restrict__ src, const int* __restrict__ dst,
    const float* __restrict__ eattr,
    const unsigned short* __restrict__ ew1f, const float* __restrict__ eb1,
    const unsigned short* __restrict__ bfrag, const float* __restrict__ eb2,
    const float* __restrict__ xin, float* __restrict__ aggr) {
  constexpr int TE = 64;
  constexpr int XS = 68;
  const int tid = threadIdx.x;
  const int e0 = blockIdx.x * TE;

  __shared__ int s_src[TE];
  __shared__ int s_dst[TE];
  __shared__ float s_x[CI][XS];
  __shared__ float s_eb2[2048];
  __shared__ unsigned short sB[3 * 8192];  // 48 KB: 3 bufs x (4 waves x 4KB tile)
  unsigned short* s_hfrag = sB + 2 * 8192; // H fragments alias buffer 2 (pre-loop only)

  if (tid < TE) { s_src[tid] = src[e0 + tid]; s_dst[tid] = dst[e0 + tid]; }
  for (int i = tid; i < CI * CO; i += 256) s_eb2[i] = eb2[i];
  __syncthreads();

  // gather x[src] -> transposed LDS
  for (int idx = tid; idx < TE * CI; idx += 256) {
    int e = idx / CI, c = idx % CI;
    float v = xin[(size_t)s_src[e] * CI + c];
    if (RELU_IN) v = fmaxf(v, 0.f);
    s_x[c][e] = v;
  }

  const int l = tid & 63, w = tid >> 6, g = l >> 4, c16 = l & 15;

  // ---- H phase via MFMA: wave w -> edge tile m=w, all 128 channels (8 MFMAs)
  {
    const int m = w;
    bf16x8 ea;
#pragma unroll
    for (int j = 0; j < 8; ++j) ea[j] = 0;
    if (g < 2) {
      const float* p = eattr + (size_t)(e0 + 16 * m + c16) * 16 + g * 8;
      f32x4 v0 = *reinterpret_cast<const f32x4*>(p);
      f32x4 v1 = *reinterpret_cast<const f32x4*>(p + 4);
#pragma unroll
      for (int j = 0; j < 4; ++j) { ea[j] = bf16rne(v0[j]); ea[4 + j] = bf16rne(v1[j]); }
    }
#pragma unroll
    for (int ct = 0; ct < 8; ++ct) {
      bf16x8 bw = *reinterpret_cast<const bf16x8*>(ew1f + (size_t)(ct * 64 + l) * 8);
      const float bb = eb1[ct * 16 + c16];
      f32x4 acc = {bb, bb, bb, bb};
      acc = __builtin_amdgcn_mfma_f32_16x16x32_bf16(ea, bw, acc, 0, 0, 0);
#pragma unroll
      for (int r = 0; r < 4; ++r) {
        const int c = ct * 16 + c16;
        s_hfrag[(((m * 4) + (c >> 5)) * 64 + ((c >> 3) & 3) * 16 + g * 4 + r) * 8 + (c & 7)] =
            bf16rne(fmaxf(acc[r], 0.f));
      }
    }
  }
  __syncthreads();

  // per-wave t-schedule:
  // L1 (CI=32): i=t, ct=t*4+w, ocol=w*16+c16
  // L2 (CI=64): i=(w>>1)+2t, ct=i*2+(w&1), ocol=(w&1)*16+c16 (i-parity split)
  const int ocol = (CI == 32) ? (w * 16 + c16) : ((w & 1) * 16 + c16);

  auto STAGE = [&](int t, int bi) {
    const int i_ = (CI == 32) ? t : ((w >> 1) + 2 * t);
    const int ct_ = (CI == 32) ? (t * 4 + w) : (i_ * 2 + (w & 1));
    const unsigned short* gp = bfrag + (size_t)ct_ * 2048 + l * 8;
    unsigned short* lp = sB + bi * 8192 + w * 2048;
#pragma unroll
    for (int kk = 0; kk < 4; ++kk) gl_lds16(gp + kk * 512, lp + kk * 512);
  };

  // stage t=0,1 (buffers 0/1 don't overlap hfrag) to overlap with afrag reads
  STAGE(0, 0);
  STAGE(1, 1);

  // A fragments reg-resident (linear conflict-free b128 reads)
  bf16x8 afrag[4][4];
#pragma unroll
  for (int m = 0; m < 4; ++m)
#pragma unroll
    for (int kk = 0; kk < 4; ++kk)
      afrag[m][kk] = *reinterpret_cast<const bf16x8*>(&s_hfrag[((m * 4 + kk) * 64 + l) * 8]);
  __syncthreads();  // all afrag reads done before buffer 2 is overwritten

  STAGE(2, 2);

  float msg[4][4];
#pragma unroll
  for (int m = 0; m < 4; ++m)
#pragma unroll
    for (int r = 0; r < 4; ++r) msg[m][r] = 0.f;

  auto CONSUME = [&](int t, int bi) {
    const int i_ = (CI == 32) ? t : ((w >> 1) + 2 * t);
    const unsigned short* lsrc = sB + bi * 8192 + w * 2048 + l * 8;
    bf16x8 bfr[4];
#pragma unroll
    for (int kk = 0; kk < 4; ++kk)
      bfr[kk] = *reinterpret_cast<const bf16x8*>(lsrc + kk * 512);
    const float bb = s_eb2[i_ * CO + ocol];
#pragma unroll
    for (int m = 0; m < 4; ++m) {
      f32x4 wacc = {0.f, 0.f, 0.f, 0.f};
#pragma unroll
      for (int kk = 0; kk < 4; ++kk)
        wacc = __builtin_amdgcn_mfma_f32_16x16x32_bf16(afrag[m][kk], bfr[kk], wacc, 0, 0, 0);
      const f32x4 xs = *reinterpret_cast<const f32x4*>(&s_x[i_][m * 16 + g * 4]);
#pragma unroll
      for (int r = 0; r < 4; ++r)
        msg[m][r] += fmaxf(wacc[r] + bb, 0.f) * xs[r];
    }
  };

  // steady state: stages t,t+1,t+2 in flight (12 loads); vmcnt(8) drains stage t.
#pragma unroll 1
  for (int t = 0; t < 29; ++t) {
    asm volatile("s_waitcnt vmcnt(8)" ::: "memory");
    const int bi = t % 3;
    CONSUME(t, bi);
    asm volatile("s_waitcnt lgkmcnt(0)" ::: "memory");  // bfr reads done before overwrite
    STAGE(t + 3, bi);
  }
  asm volatile("s_waitcnt vmcnt(8)" ::: "memory");
  CONSUME(29, 2);
  asm volatile("s_waitcnt vmcnt(4)" ::: "memory");
  CONSUME(30, 0);
  asm volatile("s_waitcnt vmcnt(0)" ::: "memory");
  CONSUME(31, 1);

  // coalesced atomics: per instruction, 4 edges x 16 consecutive cols (64B runs)
#pragma unroll
  for (int m = 0; m < 4; ++m)
#pragma unroll
    for (int r = 0; r < 4; ++r)
      atomicAdd(&aggr[(size_t)s_dst[m * 16 + g * 4 + r] * CO + ocol], msg[m][r]);
}

extern "C" void kernel_launch(void* const* d_in, const int* in_sizes, int n_in,
                              void* d_out, int out_size, void* d_ws, size_t ws_size,
                              hipStream_t stream) {
  const float* x       = (const float*)d_in[0];
  const int*   ei      = (const int*)d_in[1];
  const float* eattr   = (const float*)d_in[2];
  const float* l1_ew1  = (const float*)d_in[3];
  const float* l1_eb1  = (const float*)d_in[4];
  const float* l1_ew2  = (const float*)d_in[5];
  const float* l1_eb2  = (const float*)d_in[6];
  const float* l1_root = (const float*)d_in[7];
  const float* l1_bias = (const float*)d_in[8];
  const float* l2_ew1  = (const float*)d_in[9];
  const float* l2_eb1  = (const float*)d_in[10];
  const float* l2_ew2  = (const float*)d_in[11];
  const float* l2_eb2  = (const float*)d_in[12];
  const float* l2_root = (const float*)d_in[13];
  const float* l2_bias = (const float*)d_in[14];

  const int* src = ei;
  const int* dst = ei + NE;

  float* P1 = (float*)d_ws;                                // [N,64] pre-relu L1 out
  unsigned short* B1  = (unsigned short*)(P1 + NN * 64);   // 2048*128 bf16 ew2 frag
  unsigned short* B2  = B1 + 2048 * 128;
  unsigned short* B1e = B2 + 2048 * 128;                   // 8*64*8 bf16 ew1 frag
  unsigned short* B2e = B1e + 8 * 64 * 8;
  float* outf = (float*)d_out;

  k_reorder<<<128, 256, 0, stream>>>(l1_ew2, B1);
  k_reorder<<<128, 256, 0, stream>>>(l2_ew2, B2);
  k_reorder_e<<<1, 512, 0, stream>>>(l1_ew1, B1e);
  k_reorder_e<<<1, 512, 0, stream>>>(l2_ew1, B2e);

  k_root<32, 64, false><<<(NN * 64 + 255) / 256, 256, 0, stream>>>(x, l1_root, l1_bias, P1);
  k_edge<32, 64, false><<<NE / 64, 256, 0, stream>>>(src, dst, eattr, B1e, l1_eb1, B1, l1_eb2, x, P1);
  k_root<64, 32, true><<<(NN * 32 + 255) / 256, 256, 0, stream>>>(P1, l2_root, l2_bias, outf);
  k_edge<64, 32, true><<<NE / 64, 256, 0, stream>>>(src, dst, eattr, B2e, l2_eb1, B2, l2_eb2, P1, outf);
}